// Round 15
// baseline (116.698 us; speedup 1.0000x reference)
//
#include <hip/hip_runtime.h>
#include <hip/hip_bf16.h>
#include <stdint.h>

#define D_MODEL 1024
#define NHEADS  16
#define WINDOW  256
#define BATCH   4
#define SEQ     2048
#define NROWS   (BATCH*SEQ)   // 8192

using short8 = __attribute__((ext_vector_type(8))) short;
using f32x4  = __attribute__((ext_vector_type(4))) float;
using u32x4  = __attribute__((ext_vector_type(4))) uint32_t;
using u16x4  = __attribute__((ext_vector_type(4))) unsigned short;
typedef unsigned short u16;

// hardware RNE fp32->bf16 (compiler emits v_cvt_pk_bf16_f32; m240: scalar cast is the fast path)
__device__ __forceinline__ u16 f2b(float f) {
  __hip_bfloat16 h = __float2bfloat16(f);
  return *reinterpret_cast<u16*>(&h);
}

__device__ __forceinline__ void gload_lds16(const void* g, void* l) {
  __builtin_amdgcn_global_load_lds(
      (const __attribute__((address_space(1))) uint32_t*)g,
      (__attribute__((address_space(3))) uint32_t*)l, 16, 0, 0);
}

// ---------------- merged conversions: cast x + transpose both weight matrices ----------------
__device__ __forceinline__ void cvtT_body(const float* __restrict__ in, u16* __restrict__ out,
                                          int K, int C, int bn, int bk, int tid, float* T) {
#pragma unroll
  for (int it = 0; it < 4; ++it) {
    int c = it * 256 + tid;
    int k = c >> 4, g = c & 15;
    f32x4 v = *(const f32x4*)&in[(size_t)(bk * 64 + k) * C + bn * 64 + g * 4];
#pragma unroll
    for (int j = 0; j < 4; ++j) T[k * 65 + g * 4 + j] = v[j];
  }
  __syncthreads();
#pragma unroll
  for (int it = 0; it < 4; ++it) {
    int c = it * 256 + tid;
    int n = c >> 4, kg = c & 15;
    u16x4 o;
#pragma unroll
    for (int j = 0; j < 4; ++j) o[j] = f2b(T[(kg * 4 + j) * 65 + n]);
    *(u16x4*)&out[(size_t)(bn * 64 + n) * K + bk * 64 + kg * 4] = o;
  }
}

__global__ __launch_bounds__(256) void cvt_all_kernel(
    const float* __restrict__ x, const float* __restrict__ w_qkv, const float* __restrict__ w_out,
    u16* __restrict__ xb, u16* __restrict__ wqkvT, u16* __restrict__ woutT) {
  __shared__ float T[64 * 65];
  const int bid = blockIdx.x;
  const int tid = threadIdx.x;
  if (bid < 8192) {
    int i = bid * 256 + tid;
    f32x4 v = *(const f32x4*)(x + 4 * (size_t)i);
    u16x4 o;
    o.x = f2b(v.x); o.y = f2b(v.y); o.z = f2b(v.z); o.w = f2b(v.w);
    *(u16x4*)(xb + 4 * (size_t)i) = o;
  } else if (bid < 8192 + 768) {
    int b2 = bid - 8192;
    cvtT_body(w_qkv, wqkvT, D_MODEL, 3 * D_MODEL, b2 % 48, b2 / 48, tid, T);
  } else {
    int b3 = bid - 8960;
    cvtT_body(w_out, woutT, D_MODEL, D_MODEL, b3 % 16, b3 / 16, tid, T);
  }
}

// ---------------- GEMM: BM=256 BN=128 BK=64, 8 waves, 3-slot counted-vmcnt, 1 barrier/K-tile -----
// A [M][K] bf16, BT [N][K] bf16 (pre-transposed).
// MODE 0 (QKV): n<2048 -> qk [M][2048] bf16 ; n>=2048 -> vT [b*16+h][64 d][2048 t] bf16
// MODE 1 (out-proj): fp32 out [M][N]
template <int MODE>
__global__ __launch_bounds__(512, 2) void gemm256_kernel(
    const u16* __restrict__ A, const u16* __restrict__ BT,
    u16* __restrict__ qk, u16* __restrict__ vT, float* __restrict__ outf,
    int M, int N, int K, int nbx) {
  __shared__ short SM[3 * 24576];   // 144 KiB: per slot A[256][64] | B[128][64]

  const int tid = threadIdx.x;
  const int l = tid & 63;
  const int w = tid >> 6;
  const int wm = w >> 1, wn = w & 1;
  const int lr = l & 15, q = l >> 4;
  const int gsw = lr & 7;

  const int nwg = gridDim.x;
  const int lid = blockIdx.x;
  const int wg = (lid & 7) * (nwg >> 3) + (lid >> 3);
  const int bx = wg % nbx, by = wg / nbx;
  const int m0 = by * 256, n0 = bx * 128;

  const int NT = K >> 6;

  f32x4 acc[4][4] = {};

  auto stageA = [&](int slot, int kt) {
    short* As = SM + slot * 24576;
#pragma unroll
    for (int i = 0; i < 4; ++i) {
      int c = i * 512 + tid;
      int row = c >> 3;
      int gs = (c & 7) ^ (row & 7);
      gload_lds16(A + (size_t)(m0 + row) * K + (kt << 6) + gs * 8,
                  &As[(i * 512 + w * 64) * 8]);
    }
  };
  auto stageB = [&](int slot, int kt) {
    short* Bs = SM + slot * 24576 + 16384;
#pragma unroll
    for (int i = 0; i < 2; ++i) {
      int c = i * 512 + tid;
      int row = c >> 3;
      int gs = (c & 7) ^ (row & 7);
      gload_lds16(BT + (size_t)(n0 + row) * K + (kt << 6) + gs * 8,
                  &Bs[(i * 512 + w * 64) * 8]);
    }
  };

  stageA(0, 0); stageB(0, 0);
  stageA(1, 1); stageB(1, 1);

  int slot = 0;
  for (int t = 0; t < NT; ++t) {
    // single sync point per K-tile: tile t staged+visible, t+1's 6 loads stay in flight
    if (t + 1 < NT) { asm volatile("s_waitcnt vmcnt(6)" ::: "memory"); }
    else            { asm volatile("s_waitcnt vmcnt(0)" ::: "memory"); }
    __builtin_amdgcn_s_barrier();

    const short* As = SM + slot * 24576;
    const short* Bs = As + 16384;
    int s2 = slot + 2; if (s2 >= 3) s2 -= 3;
    const bool st = (t + 2 < NT);

#pragma unroll
    for (int kh = 0; kh < 2; ++kh) {
      short8 af[4], bfr[4];
      const int ko = (((kh << 2) | q) ^ gsw) * 8;
#pragma unroll
      for (int mf = 0; mf < 4; ++mf)
        af[mf] = *(const short8*)&As[(wm * 64 + mf * 16 + lr) * 64 + ko];
#pragma unroll
      for (int nf = 0; nf < 4; ++nf)
        bfr[nf] = *(const short8*)&Bs[(wn * 64 + nf * 16 + lr) * 64 + ko];
      if (st) { if (kh == 0) stageA(s2, t + 2); else stageB(s2, t + 2); }
      __builtin_amdgcn_s_setprio(1);
#pragma unroll
      for (int mf = 0; mf < 4; ++mf)
#pragma unroll
        for (int nf = 0; nf < 4; ++nf)
          acc[mf][nf] = __builtin_amdgcn_mfma_f32_16x16x32_bf16(af[mf], bfr[nf], acc[mf][nf], 0, 0, 0);
      __builtin_amdgcn_s_setprio(0);
    }
    slot = (slot + 1 == 3) ? 0 : slot + 1;
  }

  if (MODE == 1) {
#pragma unroll
    for (int mf = 0; mf < 4; ++mf) {
      const int m = m0 + wm * 64 + mf * 16 + q * 4;
#pragma unroll
      for (int nf = 0; nf < 4; ++nf) {
        const int n = n0 + wn * 64 + nf * 16 + lr;
#pragma unroll
        for (int r = 0; r < 4; ++r)
          outf[(size_t)(m + r) * N + n] = acc[mf][nf][r];
      }
    }
    return;
  }

  if (n0 < 2048) {
#pragma unroll
    for (int mf = 0; mf < 4; ++mf) {
      const int m = m0 + wm * 64 + mf * 16 + q * 4;
#pragma unroll
      for (int nf = 0; nf < 4; ++nf) {
        const int n = n0 + wn * 64 + nf * 16 + lr;
#pragma unroll
        for (int r = 0; r < 4; ++r)
          qk[(size_t)(m + r) * 2048 + n] = f2b(acc[mf][nf][r]);
      }
    }
  } else {
    // V region: per-wave LDS transpose of each 64x64 wave-tile, coalesced vT rows
    __syncthreads();
    short* Tw = SM + w * 1152;
    const int b = by >> 3;
    const int head = (n0 - 2048 + wn * 64) >> 6;
    const int t0 = (by & 7) * 256 + wm * 64;
    const size_t dbase = ((size_t)(b * NHEADS + head)) * 64;
#pragma unroll
    for (int nf = 0; nf < 4; ++nf) {
#pragma unroll
      for (int mf = 0; mf < 4; ++mf)
#pragma unroll
        for (int r = 0; r < 4; ++r)
          Tw[lr * 72 + mf * 16 + q * 4 + r] = (short)f2b(acc[mf][nf][r]);
      asm volatile("s_waitcnt lgkmcnt(0)" ::: "memory");
#pragma unroll
      for (int it = 0; it < 2; ++it) {
        int c = it * 64 + l;
        int row = c >> 3, off = (c & 7) * 8;
        short8 v = *(const short8*)&Tw[row * 72 + off];
        *(short8*)&vT[(dbase + nf * 16 + row) * 2048 + t0 + off] = v;
      }
      asm volatile("s_waitcnt lgkmcnt(0)" ::: "memory");
    }
  }
}

// ---------------- attention: 8 waves, 2 q-tiles/block, shared K/V staging, fixed-max softmax ------
__global__ __launch_bounds__(512) void attn_kernel(
    const u16* __restrict__ qk, const u16* __restrict__ vT, u16* __restrict__ attn) {
  __shared__ short Ks[2][64 * 72];
  __shared__ short Vs[2][64 * 72];
  __shared__ short Ps[8 * 16 * 72];

  const int tid = threadIdx.x;
  const int l = tid & 63;
  const int w = tid >> 6;
  const int wset = w >> 2;
  const int wl = w & 3;

  const int lid = blockIdx.x;
  const int xcd = lid & 7, slot = lid >> 3;
  const int bh = (slot >> 4) * 8 + xcd;
  const int qt2 = slot & 15;
  const int qtA = qt2 * 2;
  const int myqt = qtA + wset;
  const int qbase = myqt * 64;
  const int b = bh >> 4, h = bh & 15;
  const size_t rowbase = (size_t)b * 2048;
  const int lr = l & 15, lk = (l >> 4) * 8;

  const int srow = tid >> 3, soff = (tid & 7) * 8;

  u32x4 kreg, vreg;
  auto load_regs = [&](int kt) {
    const int kbase = kt * 64;
    kreg = *(const u32x4*)&qk[(rowbase + kbase + srow) * 2048 + 1024 + h * 64 + soff];
    vreg = *(const u32x4*)&vT[((size_t)bh * 64 + srow) * 2048 + kbase + soff];
  };
  auto write_lds = [&](int buf) {
    *(u32x4*)&Ks[buf][srow * 72 + soff] = kreg;
    *(u32x4*)&Vs[buf][srow * 72 + soff] = vreg;
  };

  const size_t qrowg = (rowbase + qbase + wl * 16 + lr) * 2048 + h * 64;
  short8 aq0 = *(const short8*)&qk[qrowg + lk];
  short8 aq1 = *(const short8*)&qk[qrowg + 32 + lk];

  float lsum[4] = {0.f, 0.f, 0.f, 0.f};
  f32x4 o[4] = {};

  int ktlo = qtA - 4; if (ktlo < 0) ktlo = 0;
  const int kthi = qtA + 1;

  load_regs(ktlo);
  write_lds(0);
  load_regs(ktlo + 1);
  asm volatile("s_waitcnt lgkmcnt(0)" ::: "memory");
  __builtin_amdgcn_s_barrier();

  short* Pw = &Ps[w * 16 * 72];
  int cur = 0;
  for (int kt = ktlo; kt <= kthi; ++kt) {
    const int kbase = kt * 64;
    const bool active = wset ? (kt >= myqt - 4) : (kt <= myqt);

    if (active) {
      f32x4 s[4] = {};
      __builtin_amdgcn_s_setprio(1);
#pragma unroll
      for (int fn = 0; fn < 4; ++fn) {
        short8 bk0 = *(const short8*)&Ks[cur][(fn * 16 + lr) * 72 + lk];
        short8 bk1 = *(const short8*)&Ks[cur][(fn * 16 + lr) * 72 + 32 + lk];
        s[fn] = __builtin_amdgcn_mfma_f32_16x16x32_bf16(aq0, bk0, s[fn], 0, 0, 0);
        s[fn] = __builtin_amdgcn_mfma_f32_16x16x32_bf16(aq1, bk1, s[fn], 0, 0, 0);
      }
      __builtin_amdgcn_s_setprio(0);

      f32x4 p[4];
      if (kt == myqt || kt == myqt - 4) {
        const int qrow0 = qbase + wl * 16 + (l >> 4) * 4;
#pragma unroll
        for (int fn = 0; fn < 4; ++fn) {
          int kj = kbase + fn * 16 + lr;
#pragma unroll
          for (int r = 0; r < 4; ++r) {
            int qi = qrow0 + r;
            bool ok = (kj <= qi) && (kj >= qi - WINDOW);
            p[fn][r] = ok ? __expf(s[fn][r] * 0.125f) : 0.f;
          }
        }
      } else {
#pragma unroll
        for (int fn = 0; fn < 4; ++fn)
#pragma unroll
          for (int r = 0; r < 4; ++r)
            p[fn][r] = __expf(s[fn][r] * 0.125f);
      }
#pragma unroll
      for (int r = 0; r < 4; ++r)
        lsum[r] += (p[0][r] + p[1][r]) + (p[2][r] + p[3][r]);

      // P -> per-wave LDS (A-fragment layout); same-wave DS ops are in-order,
      // so no explicit lgkmcnt needed between write and read — compiler waits the
      // true ds_read->MFMA dependency.
#pragma unroll
      for (int fn = 0; fn < 4; ++fn)
#pragma unroll
        for (int r = 0; r < 4; ++r)
          Pw[((l >> 4) * 4 + r) * 72 + fn * 16 + lr] = (short)f2b(p[fn][r]);

      __builtin_amdgcn_s_setprio(1);
#pragma unroll
      for (int ks = 0; ks < 2; ++ks) {
        short8 pa = *(const short8*)&Pw[lr * 72 + ks * 32 + lk];
#pragma unroll
        for (int fd = 0; fd < 4; ++fd) {
          short8 vb = *(const short8*)&Vs[cur][(fd * 16 + lr) * 72 + ks * 32 + lk];
          o[fd] = __builtin_amdgcn_mfma_f32_16x16x32_bf16(pa, vb, o[fd], 0, 0, 0);
        }
      }
      __builtin_amdgcn_s_setprio(0);
    }

    if (kt + 1 <= kthi) {
      write_lds(cur ^ 1);
      if (kt + 2 <= kthi) load_regs(kt + 2);
      asm volatile("s_waitcnt lgkmcnt(0)" ::: "memory");
      __builtin_amdgcn_s_barrier();
      cur ^= 1;
    }
  }

#pragma unroll
  for (int off = 1; off < 16; off <<= 1)
#pragma unroll
    for (int r = 0; r < 4; ++r) lsum[r] += __shfl_xor(lsum[r], off);

#pragma unroll
  for (int fd = 0; fd < 4; ++fd) {
#pragma unroll
    for (int r = 0; r < 4; ++r) {
      int m = qbase + wl * 16 + (l >> 4) * 4 + r;
      float val = o[fd][r] / lsum[r];
      attn[(rowbase + m) * 1024 + h * 64 + fd * 16 + lr] = f2b(val);
    }
  }
}

// ---------------- launch ----------------
extern "C" void kernel_launch(void* const* d_in, const int* in_sizes, int n_in,
                              void* d_out, int out_size, void* d_ws, size_t ws_size,
                              hipStream_t stream) {
  const float* x     = (const float*)d_in[0];
  const float* w_qkv = (const float*)d_in[1];
  const float* w_out = (const float*)d_in[2];
  float* out = (float*)d_out;
  uint8_t* ws = (uint8_t*)d_ws;

  // ws layout (bytes) — total 75,497,472
  u16* xb    = (u16*)(ws + 0);          // 8192*1024*2 = 16,777,216 ; reused as attn output
  u16* wqkvT = (u16*)(ws + 16777216);   // 3072*1024*2 =  6,291,456
  u16* woutT = (u16*)(ws + 23068672);   // 1024*1024*2 =  2,097,152
  u16* qk    = (u16*)(ws + 25165824);   // 8192*2048*2 = 33,554,432
  u16* vT    = (u16*)(ws + 58720256);   // 64*64*2048*2= 16,777,216

  cvt_all_kernel<<<8192 + 768 + 256, 256, 0, stream>>>(x, w_qkv, w_out, xb, wqkvT, woutT);

  // QKV: grid 32x24 = 768 blocks = 3 exact rounds of 256 CUs
  gemm256_kernel<0><<<(3 * D_MODEL / 128) * (NROWS / 256), 512, 0, stream>>>(
      xb, wqkvT, qk, vT, nullptr, NROWS, 3 * D_MODEL, D_MODEL, 3 * D_MODEL / 128);

  attn_kernel<<<BATCH * NHEADS * (SEQ / 128), 512, 0, stream>>>(qk, vT, xb);

  // out-proj: grid 32x8 = 256 blocks = 1 exact round
  gemm256_kernel<1><<<(D_MODEL / 128) * (NROWS / 256), 512, 0, stream>>>(
      xb, woutT, nullptr, nullptr, out, NROWS, D_MODEL, D_MODEL, D_MODEL / 128);
}

// Round 16
// 115.104 us; speedup vs baseline: 1.0138x; 1.0138x over previous
//
#include <hip/hip_runtime.h>
#include <hip/hip_bf16.h>
#include <stdint.h>

#define D_MODEL 1024
#define NHEADS  16
#define WINDOW  256
#define BATCH   4
#define SEQ     2048
#define NROWS   (BATCH*SEQ)   // 8192

using short8 = __attribute__((ext_vector_type(8))) short;
using f32x4  = __attribute__((ext_vector_type(4))) float;
using u32x4  = __attribute__((ext_vector_type(4))) uint32_t;
using u16x4  = __attribute__((ext_vector_type(4))) unsigned short;
typedef unsigned short u16;

// hardware RNE fp32->bf16
__device__ __forceinline__ u16 f2b(float f) {
  __hip_bfloat16 h = __float2bfloat16(f);
  return *reinterpret_cast<u16*>(&h);
}

__device__ __forceinline__ void gload_lds16(const void* g, void* l) {
  __builtin_amdgcn_global_load_lds(
      (const __attribute__((address_space(1))) uint32_t*)g,
      (__attribute__((address_space(3))) uint32_t*)l, 16, 0, 0);
}

// ---------------- merged conversions: cast x + transpose both weight matrices ----------------
__device__ __forceinline__ void cvtT_body(const float* __restrict__ in, u16* __restrict__ out,
                                          int K, int C, int bn, int bk, int tid, float* T) {
#pragma unroll
  for (int it = 0; it < 4; ++it) {
    int c = it * 256 + tid;
    int k = c >> 4, g = c & 15;
    f32x4 v = *(const f32x4*)&in[(size_t)(bk * 64 + k) * C + bn * 64 + g * 4];
#pragma unroll
    for (int j = 0; j < 4; ++j) T[k * 65 + g * 4 + j] = v[j];
  }
  __syncthreads();
#pragma unroll
  for (int it = 0; it < 4; ++it) {
    int c = it * 256 + tid;
    int n = c >> 4, kg = c & 15;
    u16x4 o;
#pragma unroll
    for (int j = 0; j < 4; ++j) o[j] = f2b(T[(kg * 4 + j) * 65 + n]);
    *(u16x4*)&out[(size_t)(bn * 64 + n) * K + bk * 64 + kg * 4] = o;
  }
}

__global__ __launch_bounds__(256) void cvt_all_kernel(
    const float* __restrict__ x, const float* __restrict__ w_qkv, const float* __restrict__ w_out,
    u16* __restrict__ xb, u16* __restrict__ wqkvT, u16* __restrict__ woutT) {
  __shared__ float T[64 * 65];
  const int bid = blockIdx.x;
  const int tid = threadIdx.x;
  if (bid < 8192) {
    int i = bid * 256 + tid;
    f32x4 v = *(const f32x4*)(x + 4 * (size_t)i);
    u16x4 o;
    o.x = f2b(v.x); o.y = f2b(v.y); o.z = f2b(v.z); o.w = f2b(v.w);
    *(u16x4*)(xb + 4 * (size_t)i) = o;
  } else if (bid < 8192 + 768) {
    int b2 = bid - 8192;
    cvtT_body(w_qkv, wqkvT, D_MODEL, 3 * D_MODEL, b2 % 48, b2 / 48, tid, T);
  } else {
    int b3 = bid - 8960;
    cvtT_body(w_out, woutT, D_MODEL, D_MODEL, b3 % 16, b3 / 16, tid, T);
  }
}

// ---------------- GEMM: BM=256 BN=128 BK=64, 8 waves, 3-slot counted-vmcnt, 1 barrier/K-tile -----
template <int MODE>
__global__ __launch_bounds__(512, 2) void gemm256_kernel(
    const u16* __restrict__ A, const u16* __restrict__ BT,
    u16* __restrict__ qk, u16* __restrict__ vT, float* __restrict__ outf,
    int M, int N, int K, int nbx) {
  __shared__ short SM[3 * 24576];   // 144 KiB: per slot A[256][64] | B[128][64]

  const int tid = threadIdx.x;
  const int l = tid & 63;
  const int w = tid >> 6;
  const int wm = w >> 1, wn = w & 1;
  const int lr = l & 15, q = l >> 4;
  const int gsw = lr & 7;

  const int nwg = gridDim.x;
  const int lid = blockIdx.x;
  const int wg = (lid & 7) * (nwg >> 3) + (lid >> 3);
  const int bx = wg % nbx, by = wg / nbx;
  const int m0 = by * 256, n0 = bx * 128;

  const int NT = K >> 6;

  f32x4 acc[4][4] = {};

  auto stageA = [&](int slot, int kt) {
    short* As = SM + slot * 24576;
#pragma unroll
    for (int i = 0; i < 4; ++i) {
      int c = i * 512 + tid;
      int row = c >> 3;
      int gs = (c & 7) ^ (row & 7);
      gload_lds16(A + (size_t)(m0 + row) * K + (kt << 6) + gs * 8,
                  &As[(i * 512 + w * 64) * 8]);
    }
  };
  auto stageB = [&](int slot, int kt) {
    short* Bs = SM + slot * 24576 + 16384;
#pragma unroll
    for (int i = 0; i < 2; ++i) {
      int c = i * 512 + tid;
      int row = c >> 3;
      int gs = (c & 7) ^ (row & 7);
      gload_lds16(BT + (size_t)(n0 + row) * K + (kt << 6) + gs * 8,
                  &Bs[(i * 512 + w * 64) * 8]);
    }
  };

  stageA(0, 0); stageB(0, 0);
  stageA(1, 1); stageB(1, 1);

  int slot = 0;
  for (int t = 0; t < NT; ++t) {
    if (t + 1 < NT) { asm volatile("s_waitcnt vmcnt(6)" ::: "memory"); }
    else            { asm volatile("s_waitcnt vmcnt(0)" ::: "memory"); }
    __builtin_amdgcn_s_barrier();

    const short* As = SM + slot * 24576;
    const short* Bs = As + 16384;
    int s2 = slot + 2; if (s2 >= 3) s2 -= 3;
    const bool st = (t + 2 < NT);

#pragma unroll
    for (int kh = 0; kh < 2; ++kh) {
      short8 af[4], bfr[4];
      const int ko = (((kh << 2) | q) ^ gsw) * 8;
#pragma unroll
      for (int mf = 0; mf < 4; ++mf)
        af[mf] = *(const short8*)&As[(wm * 64 + mf * 16 + lr) * 64 + ko];
#pragma unroll
      for (int nf = 0; nf < 4; ++nf)
        bfr[nf] = *(const short8*)&Bs[(wn * 64 + nf * 16 + lr) * 64 + ko];
      if (st) { if (kh == 0) stageA(s2, t + 2); else stageB(s2, t + 2); }
      __builtin_amdgcn_s_setprio(1);
#pragma unroll
      for (int mf = 0; mf < 4; ++mf)
#pragma unroll
        for (int nf = 0; nf < 4; ++nf)
          acc[mf][nf] = __builtin_amdgcn_mfma_f32_16x16x32_bf16(af[mf], bfr[nf], acc[mf][nf], 0, 0, 0);
      __builtin_amdgcn_s_setprio(0);
    }
    slot = (slot + 1 == 3) ? 0 : slot + 1;
  }

  if (MODE == 1) {
#pragma unroll
    for (int mf = 0; mf < 4; ++mf) {
      const int m = m0 + wm * 64 + mf * 16 + q * 4;
#pragma unroll
      for (int nf = 0; nf < 4; ++nf) {
        const int n = n0 + wn * 64 + nf * 16 + lr;
#pragma unroll
        for (int r = 0; r < 4; ++r)
          outf[(size_t)(m + r) * N + n] = acc[mf][nf][r];
      }
    }
    return;
  }

  if (n0 < 2048) {
#pragma unroll
    for (int mf = 0; mf < 4; ++mf) {
      const int m = m0 + wm * 64 + mf * 16 + q * 4;
#pragma unroll
      for (int nf = 0; nf < 4; ++nf) {
        const int n = n0 + wn * 64 + nf * 16 + lr;
#pragma unroll
        for (int r = 0; r < 4; ++r)
          qk[(size_t)(m + r) * 2048 + n] = f2b(acc[mf][nf][r]);
      }
    }
  } else {
    // V region: per-wave LDS transpose of each 64x64 wave-tile, coalesced vT rows
    __syncthreads();
    short* Tw = SM + w * 1152;
    const int b = by >> 3;
    const int head = (n0 - 2048 + wn * 64) >> 6;
    const int t0 = (by & 7) * 256 + wm * 64;
    const size_t dbase = ((size_t)(b * NHEADS + head)) * 64;
#pragma unroll
    for (int nf = 0; nf < 4; ++nf) {
#pragma unroll
      for (int mf = 0; mf < 4; ++mf)
#pragma unroll
        for (int r = 0; r < 4; ++r)
          Tw[lr * 72 + mf * 16 + q * 4 + r] = (short)f2b(acc[mf][nf][r]);
      asm volatile("s_waitcnt lgkmcnt(0)" ::: "memory");
#pragma unroll
      for (int it = 0; it < 2; ++it) {
        int c = it * 64 + l;
        int row = c >> 3, off = (c & 7) * 8;
        short8 v = *(const short8*)&Tw[row * 72 + off];
        *(short8*)&vT[(dbase + nf * 16 + row) * 2048 + t0 + off] = v;
      }
      asm volatile("s_waitcnt lgkmcnt(0)" ::: "memory");
    }
  }
}

// ---------------- attention: 8 waves, 2 q-tiles/block, gload_lds K/V staging, fixed-max softmax ---
// K/V tiles are GEMM-B-shaped [64][64] bf16: staged via global_load_lds (linear dest,
// pre-swizzled source granule) with XOR-swizzled reads — no reg round-trip, no pad,
// LDS 50 KB -> 3 blocks/CU. Issue stage(kt+1) at iter top (buffer freed by last barrier),
// vmcnt(0)+barrier at iter end (latency hidden under compute).
__global__ __launch_bounds__(512) void attn_kernel(
    const u16* __restrict__ qk, const u16* __restrict__ vT, u16* __restrict__ attn) {
  __shared__ short Ks[2][64 * 64];
  __shared__ short Vs[2][64 * 64];
  __shared__ short Ps[8 * 16 * 72];

  const int tid = threadIdx.x;
  const int l = tid & 63;
  const int w = tid >> 6;
  const int wset = w >> 2;
  const int wl = w & 3;

  const int lid = blockIdx.x;
  const int xcd = lid & 7, slot = lid >> 3;
  const int bh = (slot >> 4) * 8 + xcd;
  const int qt2 = slot & 15;
  const int qtA = qt2 * 2;
  const int myqt = qtA + wset;
  const int qbase = myqt * 64;
  const int b = bh >> 4, h = bh & 15;
  const size_t rowbase = (size_t)b * 2048;
  const int lr = l & 15, lk = (l >> 4) * 8;
  const int g4 = l >> 4;        // granule index of this lane's k-octet
  const int sw = lr & 7;        // read-side XOR key (row & 7)

  // staging: chunk c = tid; row = c>>3, source granule pre-swizzled
  const int srow = tid >> 3;
  const int sgs = (tid & 7) ^ (srow & 7);

  auto stage = [&](int kt, int buf) {
    const int kbase = kt * 64;
    gload_lds16(&qk[(rowbase + kbase + srow) * 2048 + 1024 + h * 64 + sgs * 8],
                &Ks[buf][(w * 64) * 8]);
    gload_lds16(&vT[((size_t)bh * 64 + srow) * 2048 + kbase + sgs * 8],
                &Vs[buf][(w * 64) * 8]);
  };

  // Q fragments once into registers
  const size_t qrowg = (rowbase + qbase + wl * 16 + lr) * 2048 + h * 64;
  short8 aq0 = *(const short8*)&qk[qrowg + lk];
  short8 aq1 = *(const short8*)&qk[qrowg + 32 + lk];

  float lsum[4] = {0.f, 0.f, 0.f, 0.f};
  f32x4 o[4] = {};

  int ktlo = qtA - 4; if (ktlo < 0) ktlo = 0;
  const int kthi = qtA + 1;

  stage(ktlo, 0);
  asm volatile("s_waitcnt vmcnt(0)" ::: "memory");
  __builtin_amdgcn_s_barrier();

  short* Pw = &Ps[w * 16 * 72];
  int cur = 0;
  for (int kt = ktlo; kt <= kthi; ++kt) {
    const int kbase = kt * 64;
    if (kt + 1 <= kthi) stage(kt + 1, cur ^ 1);   // cur^1 freed by previous iter's barrier

    const bool active = wset ? (kt >= myqt - 4) : (kt <= myqt);
    if (active) {
      // S = Q K^T (swizzled granule reads)
      f32x4 s[4] = {};
      __builtin_amdgcn_s_setprio(1);
#pragma unroll
      for (int fn = 0; fn < 4; ++fn) {
        short8 bk0 = *(const short8*)&Ks[cur][(fn * 16 + lr) * 64 + ((g4 ^ sw) * 8)];
        short8 bk1 = *(const short8*)&Ks[cur][(fn * 16 + lr) * 64 + (((4 + g4) ^ sw) * 8)];
        s[fn] = __builtin_amdgcn_mfma_f32_16x16x32_bf16(aq0, bk0, s[fn], 0, 0, 0);
        s[fn] = __builtin_amdgcn_mfma_f32_16x16x32_bf16(aq1, bk1, s[fn], 0, 0, 0);
      }
      __builtin_amdgcn_s_setprio(0);

      // P = exp(s/8), window mask only on edge tiles
      f32x4 p[4];
      if (kt == myqt || kt == myqt - 4) {
        const int qrow0 = qbase + wl * 16 + (l >> 4) * 4;
#pragma unroll
        for (int fn = 0; fn < 4; ++fn) {
          int kj = kbase + fn * 16 + lr;
#pragma unroll
          for (int r = 0; r < 4; ++r) {
            int qi = qrow0 + r;
            bool ok = (kj <= qi) && (kj >= qi - WINDOW);
            p[fn][r] = ok ? __expf(s[fn][r] * 0.125f) : 0.f;
          }
        }
      } else {
#pragma unroll
        for (int fn = 0; fn < 4; ++fn)
#pragma unroll
          for (int r = 0; r < 4; ++r)
            p[fn][r] = __expf(s[fn][r] * 0.125f);
      }
#pragma unroll
      for (int r = 0; r < 4; ++r)
        lsum[r] += (p[0][r] + p[1][r]) + (p[2][r] + p[3][r]);

      // P -> per-wave LDS (A-fragment layout); same-wave DS in-order
#pragma unroll
      for (int fn = 0; fn < 4; ++fn)
#pragma unroll
        for (int r = 0; r < 4; ++r)
          Pw[((l >> 4) * 4 + r) * 72 + fn * 16 + lr] = (short)f2b(p[fn][r]);

      // O += P V (swizzled V reads)
      __builtin_amdgcn_s_setprio(1);
#pragma unroll
      for (int ks = 0; ks < 2; ++ks) {
        short8 pa = *(const short8*)&Pw[lr * 72 + ks * 32 + lk];
#pragma unroll
        for (int fd = 0; fd < 4; ++fd) {
          short8 vb = *(const short8*)&Vs[cur][(fd * 16 + lr) * 64 + (((ks * 4 + g4) ^ sw) * 8)];
          o[fd] = __builtin_amdgcn_mfma_f32_16x16x32_bf16(pa, vb, o[fd], 0, 0, 0);
        }
      }
      __builtin_amdgcn_s_setprio(0);
    }

    if (kt + 1 <= kthi) {
      asm volatile("s_waitcnt vmcnt(0)" ::: "memory");   // stage(kt+1) landed (hidden under compute)
      __builtin_amdgcn_s_barrier();                      // visible to all; all waves done with cur
      cur ^= 1;
    }
  }

  // single cross-lane denominator reduce (16-lane row groups)
#pragma unroll
  for (int off = 1; off < 16; off <<= 1)
#pragma unroll
    for (int r = 0; r < 4; ++r) lsum[r] += __shfl_xor(lsum[r], off);

  // epilogue
#pragma unroll
  for (int fd = 0; fd < 4; ++fd) {
#pragma unroll
    for (int r = 0; r < 4; ++r) {
      int m = qbase + wl * 16 + (l >> 4) * 4 + r;
      float val = o[fd][r] / lsum[r];
      attn[(rowbase + m) * 1024 + h * 64 + fd * 16 + lr] = f2b(val);
    }
  }
}

// ---------------- launch ----------------
extern "C" void kernel_launch(void* const* d_in, const int* in_sizes, int n_in,
                              void* d_out, int out_size, void* d_ws, size_t ws_size,
                              hipStream_t stream) {
  const float* x     = (const float*)d_in[0];
  const float* w_qkv = (const float*)d_in[1];
  const float* w_out = (const float*)d_in[2];
  float* out = (float*)d_out;
  uint8_t* ws = (uint8_t*)d_ws;

  // ws layout (bytes) — total 75,497,472
  u16* xb    = (u16*)(ws + 0);          // 8192*1024*2 = 16,777,216 ; reused as attn output
  u16* wqkvT = (u16*)(ws + 16777216);   // 3072*1024*2 =  6,291,456
  u16* woutT = (u16*)(ws + 23068672);   // 1024*1024*2 =  2,097,152
  u16* qk    = (u16*)(ws + 25165824);   // 8192*2048*2 = 33,554,432
  u16* vT    = (u16*)(ws + 58720256);   // 64*64*2048*2= 16,777,216

  cvt_all_kernel<<<8192 + 768 + 256, 256, 0, stream>>>(x, w_qkv, w_out, xb, wqkvT, woutT);

  // QKV: grid 32x24 = 768 blocks = 3 exact rounds of 256 CUs
  gemm256_kernel<0><<<(3 * D_MODEL / 128) * (NROWS / 256), 512, 0, stream>>>(
      xb, wqkvT, qk, vT, nullptr, NROWS, 3 * D_MODEL, D_MODEL, 3 * D_MODEL / 128);

  attn_kernel<<<BATCH * NHEADS * (SEQ / 128), 512, 0, stream>>>(qk, vT, xb);

  // out-proj: grid 32x8 = 256 blocks = 1 exact round
  gemm256_kernel<1><<<(D_MODEL / 128) * (NROWS / 256), 512, 0, stream>>>(
      xb, woutT, nullptr, nullptr, out, NROWS, D_MODEL, D_MODEL, D_MODEL / 128);
}